// Round 8
// baseline (98.460 us; speedup 1.0000x reference)
//
#include <hip/hip_runtime.h>
#include <hip/hip_fp16.h>
#include <math.h>

#define N_IN   512
#define N_OUT  256
#define NCOEF  257
#define BATCH  1024
#define LN_EPS 1e-5f
#define G0F (-1.0f - 3.0f * (2.0f / 254.0f))

#define ROWQ 20                 // dwords per q-row: 16 data + 4 pad
#define NQ   129
#define SLABW (NQ * ROWQ)       // 2580 dwords

// physical dword of logical (q-row, o-col oo in [0,16)): quad-preserving XOR
#define SLOT(q_, oo_) ((q_) * ROWQ + (((((oo_) >> 2) ^ ((q_) & 3))) << 2) + ((oo_) & 3))

static __device__ __forceinline__ unsigned pk_bf16x2(float a, float b) {
    unsigned ua = ((__float_as_uint(a) + 0x8000u) >> 16) & 0xffffu;
    unsigned ub = (__float_as_uint(b) + 0x8000u) & 0xffff0000u;
    return ua | ub;
}

static __device__ __forceinline__ float dot2bf(unsigned w, unsigned s, float c) {
    float d;
    asm("v_dot2_f32_bf16 %0, %1, %2, %3" : "=v"(d) : "v"(w), "v"(s), "v"(c));
    return d;
}

// 6-wide even-aligned spline window: w'[j] for g = pe+j, pe = clamp(pb)&~1.
// uint4: x=(w'0,w'1) y=(w'2,w'3) z=(w'4,w'5) bf16-pairs; w = pe | f16(tanh)<<16
static __device__ __forceinline__ uint4 spline_pack(float xv) {
    const float e2 = __expf(2.f * xv);
    const float tx = 1.f - 2.f / (e2 + 1.f);        // tanh(xv)
    const float u  = (xv - G0F) * 127.f;
    const bool has = (u >= 0.f) && (u < 260.f);
    const float uf = has ? u : 0.f;
    int m = (int)uf;
    if (m > 259) m = 259;
    const float tt = uf - (float)m;
    const float t2 = tt * tt, t3 = t2 * tt;
    const float omt = 1.f - tt;
    float a0 = omt * omt * omt * (1.f / 6.f);
    float a1 = (3.f * t3 - 6.f * t2 + 4.f) * (1.f / 6.f);
    float a2 = (-3.f * t3 + 3.f * t2 + 3.f * tt + 1.f) * (1.f / 6.f);
    float a3 = t3 * (1.f / 6.f);
    if (!has) { a0 = a1 = a2 = a3 = 0.f; }
    const int pb  = m - 3;
    const int pbc = pb < 0 ? 0 : (pb > 253 ? 253 : pb);
    const int d   = pbc - pb;                       // [-3,3]
    if (d >= 1)  { a0 = a1; a1 = a2; a2 = a3; a3 = 0.f; }
    if (d >= 2)  { a0 = a1; a1 = a2; a2 = a3; a3 = 0.f; }
    if (d >= 3)  { a0 = a1; a1 = a2; a2 = a3; a3 = 0.f; }
    if (d <= -1) { a3 = a2; a2 = a1; a1 = a0; a0 = 0.f; }
    if (d <= -2) { a3 = a2; a2 = a1; a1 = a0; a0 = 0.f; }
    if (d <= -3) { a3 = a2; a2 = a1; a1 = a0; a0 = 0.f; }
    uint4 r;
    if (pbc & 1) {        // window (0,a0,a1,a2,a3,0)
        r.x = pk_bf16x2(0.f, a0);
        r.y = pk_bf16x2(a1, a2);
        r.z = pk_bf16x2(a3, 0.f);
    } else {              // window (a0,a1,a2,a3,0,0)
        r.x = pk_bf16x2(a0, a1);
        r.y = pk_bf16x2(a2, a3);
        r.z = 0u;
    }
    r.w = (unsigned)(pbc & ~1) |
          ((unsigned)__half_as_ushort(__float2half(tx)) << 16);
    return r;
}

__global__ __launch_bounds__(512, 4) void kan_main(
    const float* __restrict__ x, const float* __restrict__ W,
    const float* __restrict__ sw, float* __restrict__ part)
{
    const int bid = blockIdx.x;
    const int bc = bid & 1;             // fastest: sw-slab sharers co-resident
    const int oc = (bid >> 1) & 15;
    const int ig = bid >> 5;            // [0,16)
    const int o0 = oc * 16, i0 = ig * 32, b0 = bc * 512;
    const int t = threadIdx.x;

    __shared__ __align__(16) unsigned slab[2][2][SLABW];   // 41.3 KB total

    // staging mapping: o-row soo (fast), float4-chunk sgc (slow)
    const int soo = t & 15;             // [0,16)
    const int sgc = t >> 4;             // [0,32)

    const float* swrow = sw + ((size_t)(o0 + soo) * N_IN + i0) * NCOEF;
    const float* xp    = x + (size_t)(b0 + t) * N_IN + i0;   // own b = b0 + t

    float4 A0, B0, A1, B1;
    float t0 = 0.f, t1 = 0.f;
    float2 xc, xn, x2;

#define GLOAD(p) do {                                             \
        const float* _r0 = swrow + (size_t)(2 * (p)) * NCOEF;     \
        const float* _r1 = _r0 + NCOEF;                           \
        A0 = *(const float4*)&_r0[sgc * 4];                       \
        B0 = *(const float4*)&_r0[sgc * 4 + 128];                 \
        A1 = *(const float4*)&_r1[sgc * 4];                       \
        B1 = *(const float4*)&_r1[sgc * 4 + 128];                 \
        if (sgc == 31) { t0 = _r0[256]; t1 = _r1[256]; }          \
    } while (0)

#define STAGE(wb) do {                                            \
        unsigned* _s0 = &slab[wb][0][0];                          \
        unsigned* _s1 = &slab[wb][1][0];                          \
        const int _qa = 2 * sgc;                                  \
        _s0[SLOT(_qa,      soo)] = pk_bf16x2(A0.x, A0.y);         \
        _s0[SLOT(_qa + 1,  soo)] = pk_bf16x2(A0.z, A0.w);         \
        _s0[SLOT(_qa + 64, soo)] = pk_bf16x2(B0.x, B0.y);         \
        _s0[SLOT(_qa + 65, soo)] = pk_bf16x2(B0.z, B0.w);         \
        _s1[SLOT(_qa,      soo)] = pk_bf16x2(A1.x, A1.y);         \
        _s1[SLOT(_qa + 1,  soo)] = pk_bf16x2(A1.z, A1.w);         \
        _s1[SLOT(_qa + 64, soo)] = pk_bf16x2(B1.x, B1.y);         \
        _s1[SLOT(_qa + 65, soo)] = pk_bf16x2(B1.z, B1.w);         \
        if (sgc == 31) {                                          \
            _s0[SLOT(128, soo)] = pk_bf16x2(t0, 0.f);             \
            _s1[SLOT(128, soo)] = pk_bf16x2(t1, 0.f);             \
        }                                                         \
    } while (0)

    float acc[16];
#pragma unroll
    for (int oo = 0; oo < 16; ++oo) acc[oo] = 0.f;

    // ---- prologue: stage pair 0, prefetch pair 1
    GLOAD(0);
    xc = *(const float2*)&xp[0];
    STAGE(0);
    GLOAD(1);
    xn = *(const float2*)&xp[2];
    x2 = xn;
    __syncthreads();

    int buf = 0;
    for (int n = 0; n < 16; ++n) {
        // ---- T14: stage pair n+1 (buf^1 is free), issue loads for pair n+2
        if (n + 1 < 16) {
            STAGE(buf ^ 1);
            if (n + 2 < 16) {
                GLOAD(n + 2);
                x2 = *(const float2*)&xp[2 * (n + 2)];
            }
        }

        // ---- compute pair n from slab[buf] (own-b spline weights in regs)
#pragma unroll
        for (int sub = 0; sub < 2; ++sub) {
            const int i = i0 + 2 * n + sub;
            const uint4 u = spline_pack(sub == 0 ? xc.x : xc.y);
            const float tx =
                __half2float(__ushort_as_half((unsigned short)(u.w >> 16)));
            const float* Wrow = W + (size_t)o0 * N_IN + i;   // block-uniform
#pragma unroll
            for (int oo = 0; oo < 16; ++oo)
                acc[oo] = fmaf(tx, Wrow[(size_t)oo * N_IN], acc[oo]);
            if (u.x | u.y | u.z) {
                const int q0 = (int)(u.w & 0xffffu) >> 1;
                const unsigned* sl = &slab[buf][sub][0];
#pragma unroll
                for (int j = 0; j < 3; ++j) {
                    const int q = q0 + j;
                    const unsigned wj = (j == 0) ? u.x : (j == 1) ? u.y : u.z;
                    const unsigned* row = sl + q * ROWQ;
                    const int m = q & 3;
#pragma unroll
                    for (int lq = 0; lq < 4; ++lq) {
                        const uint4 s4 = *(const uint4*)&row[(lq ^ m) << 2];
                        acc[lq * 4 + 0] = dot2bf(wj, s4.x, acc[lq * 4 + 0]);
                        acc[lq * 4 + 1] = dot2bf(wj, s4.y, acc[lq * 4 + 1]);
                        acc[lq * 4 + 2] = dot2bf(wj, s4.z, acc[lq * 4 + 2]);
                        acc[lq * 4 + 3] = dot2bf(wj, s4.w, acc[lq * 4 + 3]);
                    }
                }
            }
        }

        __syncthreads();
        buf ^= 1;
        xc = xn;
        xn = x2;
    }

    // ---- write partial row: part[ig][b][o0..o0+15] (64 B contiguous/thread)
    float* dst = part + ((size_t)ig * BATCH + b0 + t) * N_OUT + o0;
#pragma unroll
    for (int v = 0; v < 4; ++v)
        *reinterpret_cast<float4*>(&dst[v * 4]) =
            make_float4(acc[v * 4], acc[v * 4 + 1], acc[v * 4 + 2], acc[v * 4 + 3]);
#undef GLOAD
#undef STAGE
}

__global__ __launch_bounds__(256) void kan_ln(
    const float* __restrict__ part, const float* __restrict__ prelu_a,
    float* __restrict__ out)
{
    const int b = blockIdx.x;
    const int t = threadIdx.x;

    float sv = 0.f;
#pragma unroll
    for (int k = 0; k < 16; ++k)
        sv += part[((size_t)k * BATCH + b) * N_OUT + t];

    float v1 = sv, v2 = sv * sv;
#pragma unroll
    for (int d = 1; d < 64; d <<= 1) {
        v1 += __shfl_xor(v1, d);
        v2 += __shfl_xor(v2, d);
    }
    __shared__ float r1[4], r2[4];
    if ((t & 63) == 0) { r1[t >> 6] = v1; r2[t >> 6] = v2; }
    __syncthreads();
    const float tot1 = r1[0] + r1[1] + r1[2] + r1[3];
    const float tot2 = r2[0] + r2[1] + r2[2] + r2[3];

    const float mu  = tot1 * (1.f / N_OUT);
    const float var = tot2 * (1.f / N_OUT) - mu * mu;
    const float inv = rsqrtf(var + LN_EPS);
    const float yn  = (sv - mu) * inv;
    const float a   = prelu_a[0];
    out[(size_t)b * N_OUT + t] = (yn >= 0.f) ? yn : a * yn;
}

extern "C" void kernel_launch(void* const* d_in, const int* in_sizes, int n_in,
                              void* d_out, int out_size, void* d_ws, size_t ws_size,
                              hipStream_t stream)
{
    const float* x  = (const float*)d_in[0];
    const float* W  = (const float*)d_in[1];
    const float* sw = (const float*)d_in[2];
    const float* pa = (const float*)d_in[3];
    float* out  = (float*)d_out;
    float* part = (float*)d_ws;   // 16 * 1024 * 256 floats = 16 MB

    kan_main<<<dim3(512), 512, 0, stream>>>(x, W, sw, part);
    kan_ln  <<<dim3(1024), 256, 0, stream>>>(part, pa, out);
}